// Round 5
// baseline (353.521 us; speedup 1.0000x reference)
//
#include <hip/hip_runtime.h>
#include <hip/hip_bf16.h>

// Problem constants (BLoraLinear): T=8192, D_IN=4096, D_OUT=4096, R=16, M=2, S=8
#define T_TOK 8192
#define DIN   4096
#define DOUT  4096
#define RANK  16
#define NMOD  2
#define NSEG  8

typedef __attribute__((ext_vector_type(8))) short bf16x8;
typedef __attribute__((ext_vector_type(8))) unsigned short u16x8;
typedef __attribute__((ext_vector_type(4))) float f32x4;
typedef __attribute__((ext_vector_type(16))) float f32x16;

__device__ inline unsigned short f2bf(float f) {
    union { float f; unsigned u; } v; v.f = f;
    unsigned r = v.u + 0x7FFFu + ((v.u >> 16) & 1u);   // RNE
    return (unsigned short)(r >> 16);
}

__device__ inline void gload_lds16(const void* g, void* l) {
    __builtin_amdgcn_global_load_lds(
        (const __attribute__((address_space(1))) void*)g,
        (__attribute__((address_space(3))) void*)l, 16, 0, 0);
}

// ---------------- fp32 -> bf16 cast for x and W in one launch ----------------
__global__ void cast2_bf16_kernel(const float* __restrict__ sa,
                                  unsigned short* __restrict__ da, int n8a,
                                  const float* __restrict__ sb,
                                  unsigned short* __restrict__ db, int n8b) {
    int i = blockIdx.x * blockDim.x + threadIdx.x;
    const float* s;
    unsigned short* d;
    size_t j;
    if (i < n8a) { s = sa; d = da; j = (size_t)i; }
    else if (i < n8a + n8b) { s = sb; d = db; j = (size_t)(i - n8a); }
    else return;
    const float4* s4 = (const float4*)s;
    float4 a = s4[2 * j];
    float4 b = s4[2 * j + 1];
    u16x8 o;
    o[0] = f2bf(a.x); o[1] = f2bf(a.y); o[2] = f2bf(a.z); o[3] = f2bf(a.w);
    o[4] = f2bf(b.x); o[5] = f2bf(b.y); o[6] = f2bf(b.z); o[7] = f2bf(b.w);
    *(u16x8*)(d + 8 * j) = o;
}

// ---------- At[s][m*16+r][d] = lora_A[m][s][d][r]  (bf16) --------------------
__global__ void prep_A_kernel(const float* __restrict__ A,
                              unsigned short* __restrict__ At) {
    int idx = blockIdx.x * 256 + threadIdx.x;     // NSEG*32*DIN total
    int d   = idx & (DIN - 1);
    int smr = idx >> 12;
    int s   = smr >> 5, mr = smr & 31;
    int m   = mr >> 4,  r  = mr & 15;
    float v = A[(((size_t)(m * NSEG + s) * DIN) + d) * RANK + r];
    At[idx] = f2bf(v);
}

// ---------- Bt[s][o][m*16+r] = lora_B[m][s][r][o]  (bf16) --------------------
__global__ void prep_B_kernel(const float* __restrict__ B,
                              unsigned short* __restrict__ Bt) {
    int o  = blockIdx.x * 256 + threadIdx.x;      // NSEG*DOUT total
    int s  = o >> 12;
    int oc = o & (DOUT - 1);
    unsigned short tmp[32];
    for (int m = 0; m < NMOD; ++m)
        for (int r = 0; r < RANK; ++r)
            tmp[m * 16 + r] =
                f2bf(B[(((size_t)(m * NSEG + s) * RANK) + r) * DOUT + oc]);
    for (int k = 0; k < 4; ++k) {
        u16x8 v;
        for (int j = 0; j < 8; ++j) v[j] = tmp[k * 8 + j];
        *(u16x8*)(Bt + (size_t)o * 32 + k * 8) = v;
    }
}

// ---------- u partials: Pu[ky][t][mr] = sum_{k in split} x[t,k]*At[s(t)][mr][k]
__global__ __launch_bounds__(64) void u_gemm_kernel(
    const unsigned short* __restrict__ xb, const unsigned short* __restrict__ At,
    const int* __restrict__ cu, float* __restrict__ Pu) {
    int tile = blockIdx.x;          // 0..255
    int ky   = blockIdx.y;          // 0..3
    int lane = threadIdx.x;
    int l15  = lane & 15, lk = lane >> 4;
    int t0   = tile * 32;
    f32x4 acc[2][2] = {};
    bf16x8 zero = {};
    for (int s = 0; s < NSEG; ++s) {
        int lo = cu[s], hi = cu[s + 1];
        if (hi <= t0 || lo >= t0 + 32) continue;
        const unsigned short* atb = At + (size_t)(s * 32) * DIN;
        for (int kt = 0; kt < 32; ++kt) {
            int k0 = ky * 1024 + kt * 32 + lk * 8;
            bf16x8 a[2], b[2];
            for (int mi = 0; mi < 2; ++mi) {
                int row = t0 + mi * 16 + l15;
                bf16x8 av = *(const bf16x8*)(xb + (size_t)row * DIN + k0);
                a[mi] = (row >= lo && row < hi) ? av : zero;
            }
            for (int ni = 0; ni < 2; ++ni) {
                int mr = ni * 16 + l15;
                b[ni] = *(const bf16x8*)(atb + (size_t)mr * DIN + k0);
            }
            for (int mi = 0; mi < 2; ++mi)
                for (int ni = 0; ni < 2; ++ni)
                    acc[mi][ni] = __builtin_amdgcn_mfma_f32_16x16x32_bf16(
                        a[mi], b[ni], acc[mi][ni], 0, 0, 0);
        }
    }
    for (int mi = 0; mi < 2; ++mi)
        for (int ni = 0; ni < 2; ++ni)
            for (int j = 0; j < 4; ++j) {
                int t  = t0 + mi * 16 + lk * 4 + j;
                int mr = ni * 16 + l15;
                Pu[((size_t)ky * T_TOK + t) * 32 + mr] = acc[mi][ni][j];
            }
}

// ---------- reduce 4 K-split partials -> ub bf16 [T][32] ---------------------
__global__ void reduce_u_kernel(const float* __restrict__ Pu,
                                unsigned short* __restrict__ ub) {
    int idx = blockIdx.x * 256 + threadIdx.x;   // T_TOK*32
    const size_t STRIDE = (size_t)T_TOK * 32;
    float s = Pu[idx] + Pu[idx + STRIDE] + Pu[idx + 2 * STRIDE] + Pu[idx + 3 * STRIDE];
    ub[idx] = f2bf(s);
}

// ============================================================================
// Main GEMM: 256x256 tile, BK=32, 8 waves (2Mx4N), ring-of-4 LDS (128 KiB),
// prefetch distance 3 K-tiles, counted vmcnt(4) (never 0 in main loop),
// XOR-swizzled LDS (verified: SQ_LDS_BANK_CONFLICT = 0), register read-ahead-1.
//
// Round-5 change: 32x32x16 MFMA shape (2495 TF ubench vs 2176 for 16x16x32,
// and half the MFMA instruction count -> less issue pressure in the cluster).
// Per wave per K-tile: out = 4x2 tiles of 32x32; 16 MFMA (2 k-halves),
// 12 x ds_read_b128 (A: 4mi x 2h, B: 2ni x 2h). Read split for read-ahead:
//   af2 = A-h1 of tile t (consumed this iter, drains under the h0 batch);
//   next-set = B(both h) + A-h0 of tile t+1 (consumed next iter).
// A/B frag: lane l -> row/col (l&31), k (l>>5)*8+j.  C/D: col (l&31),
// row (r&3)+8*(r>>2)+4*(l>>5)  [m74/m101 HW-verified mappings].
// ============================================================================

__device__ __forceinline__ bf16x8 lds_frag32(const char* tile, int row, int kb) {
    int rb = (row << 6) + kb;          // row*64 bytes + k-byte offset {0,16,32,48}
    rb ^= ((rb >> 7) & 7) << 4;
    return *(const bf16x8*)(tile + rb);
}

// stage one 8 KiB chunk (512 threads x 16 B) of a [256][32] bf16 tile half
__device__ __forceinline__ void stage_chunk(const unsigned short* gbase,
                                            char* lds_tile, int chunkbase, int tid) {
    int tb = chunkbase + tid * 16;
    int gb = tb ^ (((tb >> 7) & 7) << 4);
    int row = gb >> 6;
    int col = (gb & 63) >> 1;
    gload_lds16(gbase + (size_t)row * DIN + col, lds_tile + tb);
}

#define STAGE(T_)                                                              \
  {                                                                            \
    int k0s_ = (T_) * 32;                                                      \
    char* dst_ = lds + ((T_) & 3) * 32768;                                     \
    stage_chunk(xrow + k0s_, dst_, 0, tid);                                    \
    stage_chunk(xrow + k0s_, dst_, 8192, tid);                                 \
    stage_chunk(wrow_g + k0s_, dst_ + 16384, 0, tid);                          \
    stage_chunk(wrow_g + k0s_, dst_ + 16384, 8192, tid);                       \
  }

// A h=1 fragments of tile T_ (consumed THIS iteration by the h1 MFMA batch)
#define READ_AH1(T_)                                                           \
  {                                                                            \
    const char* Asl_ = lds + ((T_) & 3) * 32768;                               \
    for (int m = 0; m < 4; ++m)                                                \
        af2[m] = lds_frag32(Asl_, wrow + m * 32 + l31, 32 + kb16);             \
  }

// B (both halves) + A h=0 fragments of tile T_ (consumed NEXT iteration)
#define READ_NEXT(BFR_, AF_, T_)                                               \
  {                                                                            \
    const char* Asl_ = lds + ((T_) & 3) * 32768;                               \
    const char* Bsl_ = Asl_ + 16384;                                           \
    for (int n = 0; n < 2; ++n) {                                              \
        BFR_[n][0] = lds_frag32(Bsl_, wcol + n * 32 + l31, kb16);              \
        BFR_[n][1] = lds_frag32(Bsl_, wcol + n * 32 + l31, 32 + kb16);         \
    }                                                                          \
    for (int m = 0; m < 4; ++m)                                                \
        AF_[m] = lds_frag32(Asl_, wrow + m * 32 + l31, kb16);                  \
  }

#define CLUSTER(BFR_, AF_)                                                     \
  {                                                                            \
    __builtin_amdgcn_s_setprio(1);                                             \
    for (int m = 0; m < 4; ++m)                                                \
        for (int n = 0; n < 2; ++n)                                            \
            acc[m][n] = __builtin_amdgcn_mfma_f32_32x32x16_bf16(               \
                AF_[m], BFR_[n][0], acc[m][n], 0, 0, 0);                       \
    for (int m = 0; m < 4; ++m)                                                \
        for (int n = 0; n < 2; ++n)                                            \
            acc[m][n] = __builtin_amdgcn_mfma_f32_32x32x16_bf16(               \
                af2[m], BFR_[n][1], acc[m][n], 0, 0, 0);                       \
    __builtin_amdgcn_s_setprio(0);                                             \
  }

// U*_ = operand set read last iter (tile T_); R*_ = set to fill for T_+1.
#define ITER(UB_, UA_, RB_, RA_, T_, STG_, VM_)                                \
  {                                                                            \
    READ_AH1(T_);                                                              \
    READ_NEXT(RB_, RA_, (T_) + 1);                                             \
    if (STG_) STAGE((T_) + 3);                                                 \
    __builtin_amdgcn_sched_barrier(0);                                         \
    CLUSTER(UB_, UA_);                                                         \
    if ((VM_) == 4)      asm volatile("s_waitcnt vmcnt(4)" ::: "memory");      \
    else if ((VM_) == 0) asm volatile("s_waitcnt vmcnt(0)" ::: "memory");      \
    if ((VM_) >= 0) __builtin_amdgcn_s_barrier();                              \
  }

__global__ __launch_bounds__(512, 2) void main_gemm_kernel(
    const unsigned short* __restrict__ xb, const unsigned short* __restrict__ wb,
    const unsigned short* __restrict__ ub, const unsigned short* __restrict__ bt,
    const float* __restrict__ bias, const int* __restrict__ cu,
    float* __restrict__ out) {
    __shared__ __attribute__((aligned(1024))) char lds[131072];
    int tid  = threadIdx.x;
    int w    = tid >> 6, lane = tid & 63;
    int l31  = lane & 31;
    int kb16 = (lane >> 5) * 16;        // k-half byte offset within a 32-byte k-step
    int wrow = (w >> 2) * 128;          // wave M-offset in tile
    int wcol = (w & 3) * 64;            // wave N-offset in tile
    // XCD-aware bijective swizzle: 512 blocks, 8 XCDs, 64 per XCD
    int swz  = (blockIdx.x & 7) * 64 + (blockIdx.x >> 3);
    int row0 = (swz >> 4) * 256;
    int col0 = (swz & 15) * 256;

    const unsigned short* xrow   = xb + (size_t)row0 * DIN;
    const unsigned short* wrow_g = wb + (size_t)col0 * DIN;

    f32x16 acc[4][2] = {};
    bf16x8 bfrA[2][2], afA[4], bfrB[2][2], afB[4], af2[4];

    // prologue: stage K-tiles 0,1,2; vmcnt(4) -> tiles 0,1 resident
    STAGE(0); STAGE(1); STAGE(2);
    asm volatile("s_waitcnt vmcnt(4)" ::: "memory");
    __builtin_amdgcn_s_barrier();
    READ_NEXT(bfrA, afA, 0);

    // main loop, unrolled x2 with named register sets (no runtime indexing)
    #pragma unroll 1
    for (int t = 0; t < 124; t += 2) {
        ITER(bfrA, afA, bfrB, afB, t,     1, 4);
        ITER(bfrB, afB, bfrA, afA, t + 1, 1, 4);
    }
    // tail: t = 124..127
    ITER(bfrA, afA, bfrB, afB, 124, 1, 4);   // stages tile 127
    ITER(bfrB, afB, bfrA, afA, 125, 0, 0);   // vmcnt(0): tile 127 landed
    ITER(bfrA, afA, bfrB, afB, 126, 0, -1);  // no more barriers needed
    { READ_AH1(127); __builtin_amdgcn_sched_barrier(0); CLUSTER(bfrB, afB); }

    // fused LoRA up-projection: 2 extra K=16 MFMA steps per overlapping segment
    bf16x8 zero = {};
    for (int s = 0; s < NSEG; ++s) {
        int lo = cu[s], hi = cu[s + 1];
        if (hi <= row0 || lo >= row0 + 256) continue;
        bf16x8 au[4][2], bu[2][2];
        for (int m = 0; m < 4; ++m) {
            int row = row0 + wrow + m * 32 + l31;
            const char* ubase = (const char*)ub + (size_t)row * 64;
            bf16x8 v0 = *(const bf16x8*)(ubase + kb16);
            bf16x8 v1 = *(const bf16x8*)(ubase + 32 + kb16);
            bool in = (row >= lo && row < hi);
            au[m][0] = in ? v0 : zero;
            au[m][1] = in ? v1 : zero;
        }
        for (int n = 0; n < 2; ++n) {
            int col = col0 + wcol + n * 32 + l31;
            const char* bbase = (const char*)bt + ((size_t)s * DOUT + col) * 64;
            bu[n][0] = *(const bf16x8*)(bbase + kb16);
            bu[n][1] = *(const bf16x8*)(bbase + 32 + kb16);
        }
        for (int h = 0; h < 2; ++h)
            for (int m = 0; m < 4; ++m)
                for (int n = 0; n < 2; ++n)
                    acc[m][n] = __builtin_amdgcn_mfma_f32_32x32x16_bf16(
                        au[m][h], bu[n][h], acc[m][n], 0, 0, 0);
    }

    // epilogue: + bias, fp32 store (C/D: col = l&31, row = (r&3)+8*(r>>2)+4*(l>>5))
    float bv[2];
    for (int n = 0; n < 2; ++n) bv[n] = bias[col0 + wcol + n * 32 + l31];
    int rsub = 4 * (lane >> 5);
    for (int m = 0; m < 4; ++m) {
        int rbase = row0 + wrow + m * 32 + rsub;
        for (int n = 0; n < 2; ++n) {
            int col = col0 + wcol + n * 32 + l31;
            #pragma unroll
            for (int r = 0; r < 16; ++r) {
                int row = rbase + (r & 3) + 8 * (r >> 2);
                out[(size_t)row * DOUT + col] = acc[m][n][r] + bv[n];
            }
        }
    }
}

extern "C" void kernel_launch(void* const* d_in, const int* in_sizes, int n_in,
                              void* d_out, int out_size, void* d_ws, size_t ws_size,
                              hipStream_t stream) {
    const float* x  = (const float*)d_in[0];
    const float* W  = (const float*)d_in[1];
    const float* b  = (const float*)d_in[2];
    const float* lA = (const float*)d_in[3];
    const float* lB = (const float*)d_in[4];
    const int*   cu = (const int*)d_in[5];
    float* out = (float*)d_out;

    char* ws = (char*)d_ws;
    unsigned short* xb = (unsigned short*)(ws);                    // 64 MiB
    unsigned short* wb = (unsigned short*)(ws + 67108864);         // 32 MiB
    unsigned short* At = (unsigned short*)(ws + 100663296);        // 2 MiB
    unsigned short* Bt = (unsigned short*)(ws + 102760448);        // 2 MiB
    float*          Pu = (float*)(ws + 104857600);                 // 4 MiB
    unsigned short* ub = (unsigned short*)(ws + 109051904);        // 0.5 MiB

    const int n8x = T_TOK * DIN / 8, n8w = DOUT * DIN / 8;
    cast2_bf16_kernel<<<(n8x + n8w) / 256, 256, 0, stream>>>(x, xb, n8x, W, wb, n8w);
    prep_A_kernel<<<(NSEG * 32 * DIN) / 256, 256, 0, stream>>>(lA, At);
    prep_B_kernel<<<(NSEG * DOUT) / 256, 256, 0, stream>>>(lB, Bt);
    dim3 ug(T_TOK / 32, 4);
    u_gemm_kernel<<<ug, 64, 0, stream>>>(xb, At, cu, Pu);
    reduce_u_kernel<<<(T_TOK * 32) / 256, 256, 0, stream>>>(Pu, ub);
    dim3 mg(32 * 16);   // 512 tiles of 256x256
    main_gemm_kernel<<<mg, 512, 0, stream>>>(xb, wb, ub, Bt, b, cu, out);
}

// Round 6
// 315.970 us; speedup vs baseline: 1.1188x; 1.1188x over previous
//
#include <hip/hip_runtime.h>
#include <hip/hip_bf16.h>

// Problem constants (BLoraLinear): T=8192, D_IN=4096, D_OUT=4096, R=16, M=2, S=8
#define T_TOK 8192
#define DIN   4096
#define DOUT  4096
#define RANK  16
#define NMOD  2
#define NSEG  8

typedef __attribute__((ext_vector_type(8))) short bf16x8;
typedef __attribute__((ext_vector_type(8))) unsigned short u16x8;
typedef __attribute__((ext_vector_type(4))) float f32x4;

__device__ inline unsigned short f2bf(float f) {
    union { float f; unsigned u; } v; v.f = f;
    unsigned r = v.u + 0x7FFFu + ((v.u >> 16) & 1u);   // RNE
    return (unsigned short)(r >> 16);
}

__device__ inline void gload_lds16(const void* g, void* l) {
    __builtin_amdgcn_global_load_lds(
        (const __attribute__((address_space(1))) void*)g,
        (__attribute__((address_space(3))) void*)l, 16, 0, 0);
}

// ---------------- fp32 -> bf16 cast for x and W in one launch ----------------
__global__ void cast2_bf16_kernel(const float* __restrict__ sa,
                                  unsigned short* __restrict__ da, int n8a,
                                  const float* __restrict__ sb,
                                  unsigned short* __restrict__ db, int n8b) {
    int i = blockIdx.x * blockDim.x + threadIdx.x;
    const float* s;
    unsigned short* d;
    size_t j;
    if (i < n8a) { s = sa; d = da; j = (size_t)i; }
    else if (i < n8a + n8b) { s = sb; d = db; j = (size_t)(i - n8a); }
    else return;
    const float4* s4 = (const float4*)s;
    float4 a = s4[2 * j];
    float4 b = s4[2 * j + 1];
    u16x8 o;
    o[0] = f2bf(a.x); o[1] = f2bf(a.y); o[2] = f2bf(a.z); o[3] = f2bf(a.w);
    o[4] = f2bf(b.x); o[5] = f2bf(b.y); o[6] = f2bf(b.z); o[7] = f2bf(b.w);
    *(u16x8*)(d + 8 * j) = o;
}

// ---------- At[s][m*16+r][d] = lora_A[m][s][d][r]  (bf16) --------------------
__global__ void prep_A_kernel(const float* __restrict__ A,
                              unsigned short* __restrict__ At) {
    int idx = blockIdx.x * 256 + threadIdx.x;     // NSEG*32*DIN total
    int d   = idx & (DIN - 1);
    int smr = idx >> 12;
    int s   = smr >> 5, mr = smr & 31;
    int m   = mr >> 4,  r  = mr & 15;
    float v = A[(((size_t)(m * NSEG + s) * DIN) + d) * RANK + r];
    At[idx] = f2bf(v);
}

// ---------- Bt[s][o][m*16+r] = lora_B[m][s][r][o]  (bf16) --------------------
__global__ void prep_B_kernel(const float* __restrict__ B,
                              unsigned short* __restrict__ Bt) {
    int o  = blockIdx.x * 256 + threadIdx.x;      // NSEG*DOUT total
    int s  = o >> 12;
    int oc = o & (DOUT - 1);
    unsigned short tmp[32];
    for (int m = 0; m < NMOD; ++m)
        for (int r = 0; r < RANK; ++r)
            tmp[m * 16 + r] =
                f2bf(B[(((size_t)(m * NSEG + s) * RANK) + r) * DOUT + oc]);
    for (int k = 0; k < 4; ++k) {
        u16x8 v;
        for (int j = 0; j < 8; ++j) v[j] = tmp[k * 8 + j];
        *(u16x8*)(Bt + (size_t)o * 32 + k * 8) = v;
    }
}

// ---------- u partials: Pu[ky][t][mr] = sum_{k in split} x[t,k]*At[s(t)][mr][k]
__global__ __launch_bounds__(64) void u_gemm_kernel(
    const unsigned short* __restrict__ xb, const unsigned short* __restrict__ At,
    const int* __restrict__ cu, float* __restrict__ Pu) {
    int tile = blockIdx.x;          // 0..255
    int ky   = blockIdx.y;          // 0..3
    int lane = threadIdx.x;
    int l15  = lane & 15, lk = lane >> 4;
    int t0   = tile * 32;
    f32x4 acc[2][2] = {};
    bf16x8 zero = {};
    for (int s = 0; s < NSEG; ++s) {
        int lo = cu[s], hi = cu[s + 1];
        if (hi <= t0 || lo >= t0 + 32) continue;
        const unsigned short* atb = At + (size_t)(s * 32) * DIN;
        for (int kt = 0; kt < 32; ++kt) {
            int k0 = ky * 1024 + kt * 32 + lk * 8;
            bf16x8 a[2], b[2];
            for (int mi = 0; mi < 2; ++mi) {
                int row = t0 + mi * 16 + l15;
                bf16x8 av = *(const bf16x8*)(xb + (size_t)row * DIN + k0);
                a[mi] = (row >= lo && row < hi) ? av : zero;
            }
            for (int ni = 0; ni < 2; ++ni) {
                int mr = ni * 16 + l15;
                b[ni] = *(const bf16x8*)(atb + (size_t)mr * DIN + k0);
            }
            for (int mi = 0; mi < 2; ++mi)
                for (int ni = 0; ni < 2; ++ni)
                    acc[mi][ni] = __builtin_amdgcn_mfma_f32_16x16x32_bf16(
                        a[mi], b[ni], acc[mi][ni], 0, 0, 0);
        }
    }
    for (int mi = 0; mi < 2; ++mi)
        for (int ni = 0; ni < 2; ++ni)
            for (int j = 0; j < 4; ++j) {
                int t  = t0 + mi * 16 + lk * 4 + j;
                int mr = ni * 16 + l15;
                Pu[((size_t)ky * T_TOK + t) * 32 + mr] = acc[mi][ni][j];
            }
}

// ---------- reduce 4 K-split partials -> ub bf16 [T][32] ---------------------
__global__ void reduce_u_kernel(const float* __restrict__ Pu,
                                unsigned short* __restrict__ ub) {
    int idx = blockIdx.x * 256 + threadIdx.x;   // T_TOK*32
    const size_t STRIDE = (size_t)T_TOK * 32;
    float s = Pu[idx] + Pu[idx + STRIDE] + Pu[idx + 2 * STRIDE] + Pu[idx + 3 * STRIDE];
    ub[idx] = f2bf(s);
}

// ============================================================================
// Main GEMM — m201-style 8-phase port. 256x256 tile, BK=64, 8 waves (2Mx4N),
// 2 LDS buffers x (A[256][64] + B[256][64]) = 128 KiB, 16x16x32 MFMA.
// Per K-step: 4 phases, each { 4-8 ds_read_b128 ; 2 stage gloads ; s_barrier ;
// lgkmcnt(0) ; sched_barrier(0) ; setprio(1) ; 16 MFMA ; setprio(0) ;
// [vmcnt(2) at ph0/ph3 only] ; s_barrier }.
//
// Staging order per K-step t (for tile t+1, 2 gloads/thread/phase):
//   ph0: B c0,c1 | ph1: B c2,c3 | ph2: A c0,c1 | ph3: A c2,c3
// A-chunk row interleave (so both wave-groups' mq0 fragments land early):
//   A c0 = rows 0-63, c1 = rows 128-191, c2 = rows 64-127, c3 = rows 192-255
//   frag row:  lrow = mq*128 + whalf*64 + (m&3)*16 + l15
// Consume-vs-stage distance: B >= 3 phases, A >= 2 phases; vmcnt(2) at end of
// ph0 (covers A c2,c3 for ph1) and ph3 (covers B c0-c3 + A c0,c1 for next ph0).
// Swizzle (zero-conflict, verified R2/R4): byte ^= ((byte>>7)&7)<<4 on 128B
// rows; applied to global SOURCE of global_load_lds (linear dest) and ds_read.
// ============================================================================

__device__ __forceinline__ bf16x8 frag(const char* mat, int row, int kbyte) {
    int rb = (row << 7) + kbyte;
    rb ^= ((rb >> 7) & 7) << 4;
    return *(const bf16x8*)(mat + rb);
}

// stage chunk C_ (64 rows x 128B) of B-tile: LDS rows C_*64.., global rows = lrow
#define STAGE_B(SB_, C_, K0_)                                                  \
  { int tb = tid * 16;                                                         \
    int lrow = (C_)*64 + (tb >> 7);                                            \
    int cb = (tb & 127) ^ ((lrow & 7) << 4);                                   \
    gload_lds16(wrow_g + (size_t)lrow * DIN + (K0_) + (cb >> 1),               \
                (SB_) + (C_)*8192 + tb); }

// stage chunk C_ of A-tile with row-block interleave: global rows GB_+..
#define STAGE_A(SA_, C_, GB_, K0_)                                             \
  { int tb = tid * 16;                                                         \
    int lrow = (C_)*64 + (tb >> 7);                                            \
    int cb = (tb & 127) ^ ((lrow & 7) << 4);                                   \
    gload_lds16(xrow + (size_t)((GB_) + (tb >> 7)) * DIN + (K0_) + (cb >> 1),  \
                (SA_) + (C_)*8192 + tb); }

#define VMC(N_)                                                                \
    if ((N_) == 2)      asm volatile("s_waitcnt vmcnt(2)" ::: "memory");       \
    else if ((N_) == 0) asm volatile("s_waitcnt vmcnt(0)" ::: "memory");

#define PH_TAIL(VM_)                                                           \
    __builtin_amdgcn_s_barrier();                                              \
    asm volatile("s_waitcnt lgkmcnt(0)" ::: "memory");                         \
    __builtin_amdgcn_sched_barrier(0);                                         \
    __builtin_amdgcn_s_setprio(1);

#define PH_END(VM_)                                                            \
    __builtin_amdgcn_s_setprio(0);                                             \
    VMC(VM_);                                                                  \
    __builtin_amdgcn_s_barrier();

#define KSTEP(T_, CB_, STG_, VM0_, VM3_)                                       \
  {                                                                            \
    const char* cA  = lds + (CB_)*65536;                                       \
    const char* cBm = cA + 32768;                                              \
    char* sA = lds + (1 - (CB_))*65536;                                        \
    char* sB = sA + 32768;                                                     \
    const int k0n = ((T_) + 1) * 64;                                           \
    bf16x8 af[4], bf0[4], bf1[4];                                              \
    /* ---- ph0: B-k0 + A-mq0-k0 reads; stage B c0,c1; MFMA [0-3][n] k0 ---- */\
    for (int n = 0; n < 4; ++n) bf0[n] = frag(cBm, wcol + n*16 + l15, lk*16);  \
    for (int m = 0; m < 4; ++m) af[m]  = frag(cA, whalf*64 + m*16 + l15, lk*16);\
    if (STG_) { STAGE_B(sB, 0, k0n); STAGE_B(sB, 1, k0n); }                    \
    PH_TAIL(VM0_);                                                             \
    for (int m = 0; m < 4; ++m) for (int n = 0; n < 4; ++n)                    \
        acc[m][n] = __builtin_amdgcn_mfma_f32_16x16x32_bf16(                   \
            af[m], bf0[n], acc[m][n], 0, 0, 0);                                \
    PH_END(VM0_);                                                              \
    /* ---- ph1: A-mq1-k0 reads; stage B c2,c3; MFMA [4-7][n] k0 ---- */       \
    for (int m = 0; m < 4; ++m)                                                \
        af[m] = frag(cA, 128 + whalf*64 + m*16 + l15, lk*16);                  \
    if (STG_) { STAGE_B(sB, 2, k0n); STAGE_B(sB, 3, k0n); }                    \
    PH_TAIL(-1);                                                               \
    for (int m = 0; m < 4; ++m) for (int n = 0; n < 4; ++n)                    \
        acc[4 + m][n] = __builtin_amdgcn_mfma_f32_16x16x32_bf16(               \
            af[m], bf0[n], acc[4 + m][n], 0, 0, 0);                            \
    PH_END(-1);                                                                \
    /* ---- ph2: B-k1 + A-mq0-k1 reads; stage A c0,c1; MFMA [0-3][n] k1 ---- */\
    for (int n = 0; n < 4; ++n)                                                \
        bf1[n] = frag(cBm, wcol + n*16 + l15, 64 + lk*16);                     \
    for (int m = 0; m < 4; ++m)                                                \
        af[m] = frag(cA, whalf*64 + m*16 + l15, 64 + lk*16);                   \
    if (STG_) { STAGE_A(sA, 0, 0, k0n); STAGE_A(sA, 1, 128, k0n); }            \
    PH_TAIL(-1);                                                               \
    for (int m = 0; m < 4; ++m) for (int n = 0; n < 4; ++n)                    \
        acc[m][n] = __builtin_amdgcn_mfma_f32_16x16x32_bf16(                   \
            af[m], bf1[n], acc[m][n], 0, 0, 0);                                \
    PH_END(-1);                                                                \
    /* ---- ph3: A-mq1-k1 reads; stage A c2,c3; MFMA [4-7][n] k1 ---- */       \
    for (int m = 0; m < 4; ++m)                                                \
        af[m] = frag(cA, 128 + whalf*64 + m*16 + l15, 64 + lk*16);             \
    if (STG_) { STAGE_A(sA, 2, 64, k0n); STAGE_A(sA, 3, 192, k0n); }           \
    PH_TAIL(VM3_);                                                             \
    for (int m = 0; m < 4; ++m) for (int n = 0; n < 4; ++n)                    \
        acc[4 + m][n] = __builtin_amdgcn_mfma_f32_16x16x32_bf16(               \
            af[m], bf1[n], acc[4 + m][n], 0, 0, 0);                            \
    PH_END(VM3_);                                                              \
  }

__global__ __launch_bounds__(512, 2) void main_gemm_kernel(
    const unsigned short* __restrict__ xb, const unsigned short* __restrict__ wb,
    const unsigned short* __restrict__ ub, const unsigned short* __restrict__ bt,
    const float* __restrict__ bias, const int* __restrict__ cu,
    float* __restrict__ out) {
    __shared__ __attribute__((aligned(1024))) char lds[131072];
    int tid   = threadIdx.x;
    int w     = tid >> 6, lane = tid & 63;
    int l15   = lane & 15, lk = lane >> 4;
    int whalf = w >> 2;                 // wave M-group (0/1)
    int wrow  = whalf * 128;            // wave M-offset in tile
    int wcol  = (w & 3) * 64;           // wave N-offset in tile
    // XCD-aware bijective swizzle: 512 blocks, 8 XCDs, 64 per XCD
    int swz  = (blockIdx.x & 7) * 64 + (blockIdx.x >> 3);
    int row0 = (swz >> 4) * 256;
    int col0 = (swz & 15) * 256;

    const unsigned short* xrow   = xb + (size_t)row0 * DIN;
    const unsigned short* wrow_g = wb + (size_t)col0 * DIN;

    f32x4 acc[8][4] = {};

    // prologue: stage tile 0 into buffer 0, loads ordered as steady state
    {
        char* sA = lds;
        char* sB = lds + 32768;
        STAGE_B(sB, 0, 0); STAGE_B(sB, 1, 0);
        STAGE_B(sB, 2, 0); STAGE_B(sB, 3, 0);
        STAGE_A(sA, 0, 0, 0); STAGE_A(sA, 1, 128, 0);
        STAGE_A(sA, 2, 64, 0); STAGE_A(sA, 3, 192, 0);
    }
    asm volatile("s_waitcnt vmcnt(2)" ::: "memory");
    __builtin_amdgcn_s_barrier();

    // main loop: 64 K-steps of 64
    #pragma unroll 1
    for (int t = 0; t < 62; t += 2) {
        KSTEP(t,     0, 1, 2, 2);
        KSTEP(t + 1, 1, 1, 2, 2);
    }
    KSTEP(62, 0, 1, 2, 2);
    KSTEP(63, 1, 0, 0, -1);

    // fused LoRA up-projection: one extra K=32 MFMA step per overlapping segment
    bf16x8 zero = {};
    for (int s = 0; s < NSEG; ++s) {
        int lo = cu[s], hi = cu[s + 1];
        if (hi <= row0 || lo >= row0 + 256) continue;
        bf16x8 au[8], bu[4];
        for (int m = 0; m < 8; ++m) {
            int row = row0 + wrow + m * 16 + l15;
            bf16x8 v = *(const bf16x8*)(ub + (size_t)row * 32 + lk * 8);
            au[m] = (row >= lo && row < hi) ? v : zero;
        }
        for (int n = 0; n < 4; ++n) {
            int col = col0 + wcol + n * 16 + l15;
            bu[n] = *(const bf16x8*)(bt + ((size_t)s * DOUT + col) * 32 + lk * 8);
        }
        for (int m = 0; m < 8; ++m)
            for (int n = 0; n < 4; ++n)
                acc[m][n] = __builtin_amdgcn_mfma_f32_16x16x32_bf16(
                    au[m], bu[n], acc[m][n], 0, 0, 0);
    }

    // epilogue: + bias, fp32 store
    float bv[4];
    for (int n = 0; n < 4; ++n) bv[n] = bias[col0 + wcol + n * 16 + l15];
    for (int m = 0; m < 8; ++m) {
        int rbase = row0 + wrow + m * 16 + lk * 4;
        for (int n = 0; n < 4; ++n) {
            int col = col0 + wcol + n * 16 + l15;
            for (int jj = 0; jj < 4; ++jj)
                out[(size_t)(rbase + jj) * DOUT + col] = acc[m][n][jj] + bv[n];
        }
    }
}

extern "C" void kernel_launch(void* const* d_in, const int* in_sizes, int n_in,
                              void* d_out, int out_size, void* d_ws, size_t ws_size,
                              hipStream_t stream) {
    const float* x  = (const float*)d_in[0];
    const float* W  = (const float*)d_in[1];
    const float* b  = (const float*)d_in[2];
    const float* lA = (const float*)d_in[3];
    const float* lB = (const float*)d_in[4];
    const int*   cu = (const int*)d_in[5];
    float* out = (float*)d_out;

    char* ws = (char*)d_ws;
    unsigned short* xb = (unsigned short*)(ws);                    // 64 MiB
    unsigned short* wb = (unsigned short*)(ws + 67108864);         // 32 MiB
    unsigned short* At = (unsigned short*)(ws + 100663296);        // 2 MiB
    unsigned short* Bt = (unsigned short*)(ws + 102760448);        // 2 MiB
    float*          Pu = (float*)(ws + 104857600);                 // 4 MiB
    unsigned short* ub = (unsigned short*)(ws + 109051904);        // 0.5 MiB

    const int n8x = T_TOK * DIN / 8, n8w = DOUT * DIN / 8;
    cast2_bf16_kernel<<<(n8x + n8w) / 256, 256, 0, stream>>>(x, xb, n8x, W, wb, n8w);
    prep_A_kernel<<<(NSEG * 32 * DIN) / 256, 256, 0, stream>>>(lA, At);
    prep_B_kernel<<<(NSEG * DOUT) / 256, 256, 0, stream>>>(lB, Bt);
    dim3 ug(T_TOK / 32, 4);
    u_gemm_kernel<<<ug, 64, 0, stream>>>(xb, At, cu, Pu);
    reduce_u_kernel<<<(T_TOK * 32) / 256, 256, 0, stream>>>(Pu, ub);
    dim3 mg(32 * 16);   // 512 tiles of 256x256
    main_gemm_kernel<<<mg, 512, 0, stream>>>(xb, wb, ub, Bt, b, cu, out);
}